// Round 4
// baseline (538.754 us; speedup 1.0000x reference)
//
#include <hip/hip_runtime.h>

// ---------------------------------------------------------------------------
// MHA block: x[4,1024,2048], W*[2048,2048] (torch Linear: y = x @ W^T)
//   q,k,v = x@W{q,k,v}^T ; scores = q k^T * sqrt(128) (causal) ; softmax ;
//   ctx = attn @ v ; out = ctx @ Wo^T
// f16 MFMA everywhere; Q/K path hi/lo f16 split (lo scaled 2^11) for
// fp32-grade logits (softmax is near-argmax: logit std ~100).
// R3: gemm_split -> 8-wave tri-buffered deep pipeline (T3+T4+T5 on top of
// R2's T2 swizzle): counted vmcnt(4) at tile boundaries (never 0 mid-loop),
// 2 phases/tile with {ds_read || gld16-issue -> bar -> lgkm0 -> 12 MFMA -> bar}.
// ---------------------------------------------------------------------------

typedef _Float16 f16;
typedef _Float16 f16x8 __attribute__((ext_vector_type(8)));
typedef _Float16 f16x4 __attribute__((ext_vector_type(4)));
typedef float f32x4 __attribute__((ext_vector_type(4)));

__device__ __forceinline__ f32x4 mfma16(f16x8 a, f16x8 b, f32x4 c) {
  return __builtin_amdgcn_mfma_f32_16x16x32_f16(a, b, c, 0, 0, 0);
}

__device__ __forceinline__ void gld16(const void* g, void* l) {
  __builtin_amdgcn_global_load_lds(
      (const __attribute__((address_space(1))) void*)g,
      (__attribute__((address_space(3))) void*)l, 16, 0, 0);
}

#define BAR() __builtin_amdgcn_s_barrier()
#define VMCNT4() asm volatile("s_waitcnt vmcnt(4)" ::: "memory")
#define VMCNT0() asm volatile("s_waitcnt vmcnt(0)" ::: "memory")
#define LGKM0()                                        \
  do {                                                 \
    asm volatile("s_waitcnt lgkmcnt(0)" ::: "memory"); \
    __builtin_amdgcn_sched_barrier(0);                 \
  } while (0)

static constexpr float LO_SCALE  = 2048.0f;   // 2^11
static constexpr float LO_INV    = 1.0f / 2048.0f;

// ---------------- conversion kernels ----------------
__global__ void conv_split_k(const float* __restrict__ src,
                             f16* __restrict__ hi, f16* __restrict__ lo, int n4) {
  int i = blockIdx.x * 256 + threadIdx.x;
  if (i >= n4) return;
  float4 v = reinterpret_cast<const float4*>(src)[i];
  f16x4 h, l;
  f16 t;
  t = (f16)v.x; h[0] = t; l[0] = (f16)((v.x - (float)t) * LO_SCALE);
  t = (f16)v.y; h[1] = t; l[1] = (f16)((v.y - (float)t) * LO_SCALE);
  t = (f16)v.z; h[2] = t; l[2] = (f16)((v.z - (float)t) * LO_SCALE);
  t = (f16)v.w; h[3] = t; l[3] = (f16)((v.w - (float)t) * LO_SCALE);
  reinterpret_cast<f16x4*>(hi)[i] = h;
  reinterpret_cast<f16x4*>(lo)[i] = l;
}

__global__ void conv_plain_k(const float* __restrict__ src, f16* __restrict__ dst, int n4) {
  int i = blockIdx.x * 256 + threadIdx.x;
  if (i >= n4) return;
  float4 v = reinterpret_cast<const float4*>(src)[i];
  f16x4 h;
  h[0] = (f16)v.x; h[1] = (f16)v.y; h[2] = (f16)v.z; h[3] = (f16)v.w;
  reinterpret_cast<f16x4*>(dst)[i] = h;
}

// ---------------- plain GEMM: C[M,N] = A[M,K] * B[N,K]^T ----------------
// 128x128 tile, BK=32, 256 threads (4 waves, 2x2 of 64x64), m97 2-barrier loop.
// OUTMODE: 0 = f16, 2 = f32
template<int OUTMODE>
__global__ __launch_bounds__(256, 2) void gemm_bt(
    const f16* __restrict__ Ah, const f16* __restrict__ Bh,
    void* __restrict__ C0, int Nn, int Kk)
{
  __shared__ f16 sAh[128 * 32];
  __shared__ f16 sBh[128 * 32];

  const int t = threadIdx.x;
  const int wave = t >> 6, lane = t & 63;
  const int l15 = lane & 15, lg = lane >> 4;
  const int wr = wave >> 1, wc = wave & 1;
  const long m0 = (long)blockIdx.y * 128, n0 = (long)blockIdx.x * 128;

  const int srow = t >> 2;            // 0..63
  const int scol = (t & 3) * 8;
  const long aoff = (m0 + srow) * (long)Kk + scol;
  const long boff = (n0 + srow) * (long)Kk + scol;
  const long rowstep = 64L * Kk;
  const int ldst = wave * 512;        // f16 elements, wave-uniform

  f32x4 acc[4][4] = {};
  const int lof = l15 * 32 + lg * 8;

  for (int k0 = 0; k0 < Kk; k0 += 32) {
    gld16(Ah + aoff + k0,           sAh + ldst);
    gld16(Ah + aoff + rowstep + k0, sAh + 2048 + ldst);
    gld16(Bh + boff + k0,           sBh + ldst);
    gld16(Bh + boff + rowstep + k0, sBh + 2048 + ldst);
    __syncthreads();
    f16x8 a_h[4], b_h[4];
#pragma unroll
    for (int i = 0; i < 4; ++i) a_h[i] = *(const f16x8*)(sAh + (wr * 64 + i * 16) * 32 + lof);
#pragma unroll
    for (int j = 0; j < 4; ++j) b_h[j] = *(const f16x8*)(sBh + (wc * 64 + j * 16) * 32 + lof);
#pragma unroll
    for (int i = 0; i < 4; ++i)
#pragma unroll
      for (int j = 0; j < 4; ++j)
        acc[i][j] = mfma16(a_h[i], b_h[j], acc[i][j]);
    __syncthreads();
  }

#pragma unroll
  for (int i = 0; i < 4; ++i)
#pragma unroll
    for (int j = 0; j < 4; ++j)
#pragma unroll
      for (int r = 0; r < 4; ++r) {
        long row = m0 + wr * 64 + i * 16 + lg * 4 + r;
        long col = n0 + wc * 64 + j * 16 + l15;
        long idx = row * Nn + col;
        float v = acc[i][j][r];
        if constexpr (OUTMODE == 0) {
          ((f16*)C0)[idx] = (f16)v;
        } else {
          ((float*)C0)[idx] = v;
        }
      }
}

// ---------------- split GEMM, 8-wave tri-buffered pipeline ----------------
// C = (Ah+Al/2048)(Bh+Bl/2048)^T, drop lo*lo. 128x128 tile, BK=32, 512 thr.
// LDS: 3 buffers x (sA[128][64] + sB[128][64]) = 96 KB; hi in cols 0..31,
// lo in 32..63, XOR-swizzled byte ^= ((row&7)<<4) (conflict-free, R2-verified).
// Pipeline: computing tile t (buf t%3) while tile t+1 lands and tile t+2 is
// issued -> boundary wait = counted vmcnt(4) (own t+2 loads outstanding).
// Per tile 2 phases; per phase: {ds_read subtile; issue 2 gld16; barrier;
// lgkmcnt(0)+sched_barrier; setprio(1); 12 MFMA; setprio(0); barrier}.
__global__ __launch_bounds__(512, 2) void gemm_split(
    const f16* __restrict__ Ah, const f16* __restrict__ Al,
    const f16* __restrict__ Bh, const f16* __restrict__ Bl,
    f16* __restrict__ Chi, f16* __restrict__ Clo, int Nn, int Kk)
{
  __shared__ f16 sA[3][128 * 64];
  __shared__ f16 sB[3][128 * 64];

  const int t = threadIdx.x;          // 0..511
  const int wave = t >> 6, lane = t & 63;
  const int l15 = lane & 15, lg = lane >> 4;
  const int wr = wave >> 2, wc = wave & 3;    // 2 x 4 wave grid, 64x32 each
  const long m0 = (long)blockIdx.y * 128, n0 = (long)blockIdx.x * 128;

  // ---- staging precompute: 2 slots/thread/array; slot = q*512 + t.
  // phys byte = slot*16; row = slot>>3; within-row phys = (slot&7)*16.
  // logical byte = phys ^ ((row&7)<<4) -> f16 col 0..63 -> hi/lo + k (0..31).
  const int slot0 = t, slot1 = t + 512;
  const int srow0 = slot0 >> 3, srow1 = slot1 >> 3;
  const int cf0 = ((((slot0 & 7) * 16) ^ ((srow0 & 7) << 4)) >> 1);
  const int cf1 = ((((slot1 & 7) * 16) ^ ((srow1 & 7) << 4)) >> 1);
  const f16* gA0 = (cf0 >= 32 ? Al : Ah) + (m0 + srow0) * (long)Kk + (cf0 & 31);
  const f16* gA1 = (cf1 >= 32 ? Al : Ah) + (m0 + srow1) * (long)Kk + (cf1 & 31);
  const f16* gB0 = (cf0 >= 32 ? Bl : Bh) + (n0 + srow0) * (long)Kk + (cf0 & 31);
  const f16* gB1 = (cf1 >= 32 ? Bl : Bh) + (n0 + srow1) * (long)Kk + (cf1 & 31);
  const int ds0 = slot0 * 8, ds1 = slot1 * 8;

  // ---- read precompute: frag row = base16 + l15
  const int r7x = (l15 & 7) << 4;                // row-XOR bits (bytes)
  const int ch = ((lg * 16) ^ r7x) >> 1;         // hi frag col (f16)
  const int cl = ((64 + lg * 16) ^ r7x) >> 1;    // lo frag col (f16)

  f32x4 acc[4][2] = {};
  f32x4 accc[4][2] = {};

  const int NT = Kk >> 5;   // 64 K-tiles

  // ---- prologue: stage tiles 0 and 1
  gld16(gA0, &sA[0][ds0]); gld16(gA1, &sA[0][ds1]);
  gld16(gB0, &sB[0][ds0]); gld16(gB1, &sB[0][ds1]);
  gld16(gA0 + 32, &sA[1][ds0]); gld16(gA1 + 32, &sA[1][ds1]);
  gld16(gB0 + 32, &sB[1][ds0]); gld16(gB1 + 32, &sB[1][ds1]);
  VMCNT4();   // tile 0 landed (tile 1's 4 may be outstanding)
  BAR();

  int cur = 0;
  for (int kt = 0; kt < NT; ++kt) {
    const f16* sAc = &sA[cur][0];
    const f16* sBc = &sB[cur][0];
    int nb = cur + 2; if (nb >= 3) nb -= 3;
    const bool more = (kt + 2) < NT;
    const long ko = (long)(kt + 2) * 32;

    // ---------- phase 1: rows 0,1 ----------
    f16x8 a_h[2], a_l[2], b_h[2], b_l[2];
#pragma unroll
    for (int i = 0; i < 2; ++i) {
      const int row = wr * 64 + i * 16 + l15;
      a_h[i] = *(const f16x8*)(sAc + row * 64 + ch);
      a_l[i] = *(const f16x8*)(sAc + row * 64 + cl);
    }
#pragma unroll
    for (int j = 0; j < 2; ++j) {
      const int row = wc * 32 + j * 16 + l15;
      b_h[j] = *(const f16x8*)(sBc + row * 64 + ch);
      b_l[j] = *(const f16x8*)(sBc + row * 64 + cl);
    }
    if (more) {
      gld16(gA0 + ko, &sA[nb][ds0]);
      gld16(gA1 + ko, &sA[nb][ds1]);
    }
    BAR();
    LGKM0();
    __builtin_amdgcn_s_setprio(1);
#pragma unroll
    for (int i = 0; i < 2; ++i)
#pragma unroll
      for (int j = 0; j < 2; ++j) {
        acc[i][j]  = mfma16(a_h[i], b_h[j], acc[i][j]);
        accc[i][j] = mfma16(a_h[i], b_l[j], accc[i][j]);
        accc[i][j] = mfma16(a_l[i], b_h[j], accc[i][j]);
      }
    __builtin_amdgcn_s_setprio(0);
    BAR();

    // ---------- phase 2: rows 2,3 ----------
    f16x8 c_h[2], c_l[2];
#pragma unroll
    for (int i = 0; i < 2; ++i) {
      const int row = wr * 64 + (i + 2) * 16 + l15;
      c_h[i] = *(const f16x8*)(sAc + row * 64 + ch);
      c_l[i] = *(const f16x8*)(sAc + row * 64 + cl);
    }
    if (more) {
      gld16(gB0 + ko, &sB[nb][ds0]);
      gld16(gB1 + ko, &sB[nb][ds1]);
    }
    BAR();
    LGKM0();
    __builtin_amdgcn_s_setprio(1);
#pragma unroll
    for (int i = 0; i < 2; ++i)
#pragma unroll
      for (int j = 0; j < 2; ++j) {
        acc[i + 2][j]  = mfma16(c_h[i], b_h[j], acc[i + 2][j]);
        accc[i + 2][j] = mfma16(c_h[i], b_l[j], accc[i + 2][j]);
        accc[i + 2][j] = mfma16(c_l[i], b_h[j], accc[i + 2][j]);
      }
    __builtin_amdgcn_s_setprio(0);

    // ---------- tile boundary ----------
    if (kt < NT - 1) {
      if (kt == NT - 2) VMCNT0(); else VMCNT4();
      BAR();
    }
    cur = cur + 1; if (cur == 3) cur = 0;
  }

#pragma unroll
  for (int i = 0; i < 4; ++i)
#pragma unroll
    for (int j = 0; j < 2; ++j)
#pragma unroll
      for (int r = 0; r < 4; ++r) {
        long row = m0 + wr * 64 + i * 16 + lg * 4 + r;
        long col = n0 + wc * 32 + j * 16 + l15;
        long idx = row * Nn + col;
        float v = acc[i][j][r] + accc[i][j][r] * LO_INV;
        f16 hh = (f16)v;
        Chi[idx] = hh;
        Clo[idx] = (f16)((v - (float)hh) * LO_SCALE);
      }
}

// ---------------- V transpose: V[b*1024+s][h*128+d] -> Vt[(b*16+h)*128+d][s] ---
__global__ void transpose_v_k(const f16* __restrict__ V, f16* __restrict__ Vt) {
  const int st = blockIdx.x;      // 16 s-tiles of 64
  const int dt = blockIdx.y;      // 2 d-tiles of 64
  const int bh = blockIdx.z;      // 64
  const int b = bh >> 4, h = bh & 15;
  __shared__ f16 tile[64][68];
  const int t = threadIdx.x;
  const int r = t >> 4;
  const int c4 = (t & 15) * 4;
#pragma unroll
  for (int p = 0; p < 4; ++p) {
    int row = r + p * 16;
    f16x4 v = *(const f16x4*)(V + (long)(b * 1024 + st * 64 + row) * 2048 + h * 128 + dt * 64 + c4);
    tile[row][c4] = v[0]; tile[row][c4 + 1] = v[1];
    tile[row][c4 + 2] = v[2]; tile[row][c4 + 3] = v[3];
  }
  __syncthreads();
#pragma unroll
  for (int p = 0; p < 4; ++p) {
    int drow = r + p * 16;
    f16x4 o;
    o[0] = tile[c4][drow]; o[1] = tile[c4 + 1][drow];
    o[2] = tile[c4 + 2][drow]; o[3] = tile[c4 + 3][drow];
    *(f16x4*)(Vt + ((long)bh * 128 + dt * 64 + drow) * 1024 + st * 64 + c4) = o;
  }
}

// ---------------- causal flash attention ----------------
// grid (64 = h*4+b groups, 8 = p), 256 thr / 4 waves; each wave owns 16 q-rows.
// Block p processes q-tiles (15-p) then (p): uniform 17 k-tiles per block.
// K(hi,lo) and V staged in LDS via gld16, XOR-swizzled.
__global__ __launch_bounds__(256, 2) void attn_k(
    const f16* __restrict__ Qh, const f16* __restrict__ Ql,
    const f16* __restrict__ Kh, const f16* __restrict__ Kl,
    const f16* __restrict__ Vt, f16* __restrict__ Ctx)
{
  const int g = blockIdx.x;           // h*4 + b
  const int p = blockIdx.y;           // 0..7
  const int b = g & 3, h = g >> 2;
  const int t = threadIdx.x, wave = t >> 6, lane = t & 63;
  const int l15 = lane & 15, lg = lane >> 4;

  __shared__ f16 sKh[64 * 128];       // [krow][d], swizzled
  __shared__ f16 sKl[64 * 128];
  __shared__ f16 sV [128 * 64];       // [d][s], swizzled
  __shared__ f16 pbuf[4][16 * 72];    // per-wave P^T staging

  const long kbase = (long)(b * 1024) * 2048 + h * 128;
  const long vtb = (long)((b * 16 + h) * 128) * 1024;
  const float SC2 = (float)(11.313708498984761 * 1.4426950408889634);

  const int krow_s = t >> 4;                       // + q*16
  const int vrow_s = t >> 3;                       // + q*32

#pragma unroll
  for (int half = 0; half < 2; ++half) {
    const int myqt = half ? p : 15 - p;
    const int qbase = myqt * 64 + wave * 16;

    f16x8 q_h[4], q_l[4];
#pragma unroll
    for (int c = 0; c < 4; ++c) {
      long o8 = (long)(b * 1024 + qbase + l15) * 2048 + h * 128 + c * 32 + lg * 8;
      q_h[c] = *(const f16x8*)(Qh + o8);
      q_l[c] = *(const f16x8*)(Ql + o8);
    }

    float mm[4], ll[4];
#pragma unroll
    for (int r = 0; r < 4; ++r) { mm[r] = -1e30f; ll[r] = 0.f; }
    f32x4 o[8] = {};

    const int nt = myqt + 1;
    for (int kt = 0; kt < nt; ++kt) {
      const int k0 = kt * 64;
#pragma unroll
      for (int q = 0; q < 4; ++q) {
        const int row = q * 16 + krow_s;
        const int colx = ((t & 15) * 8) ^ ((row & 7) << 3);
        gld16(Kh + kbase + (long)(k0 + row) * 2048 + colx, sKh + q * 2048 + t * 8);
        gld16(Kl + kbase + (long)(k0 + row) * 2048 + colx, sKl + q * 2048 + t * 8);
      }
#pragma unroll
      for (int q = 0; q < 4; ++q) {
        const int row = q * 32 + vrow_s;
        const int colx = ((t & 7) * 8) ^ ((row & 7) << 3);
        gld16(Vt + vtb + (long)row * 1024 + k0 + colx, sV + q * 2048 + t * 8);
      }
      __syncthreads();

      f32x4 s[4] = {};
      f32x4 sc[4] = {};
#pragma unroll
      for (int c = 0; c < 4; ++c)
#pragma unroll
        for (int j = 0; j < 4; ++j) {
          const int krow = j * 16 + l15;
          const int koff = krow * 128 + (((c * 32 + lg * 8)) ^ ((krow & 7) << 3));
          f16x8 kh = *(const f16x8*)(sKh + koff);
          f16x8 kl = *(const f16x8*)(sKl + koff);
          s[j]  = mfma16(q_h[c], kh, s[j]);
          sc[j] = mfma16(q_h[c], kl, sc[j]);
          sc[j] = mfma16(q_l[c], kh, sc[j]);
        }
#pragma unroll
      for (int j = 0; j < 4; ++j)
        s[j] = s[j] + sc[j] * LO_INV;

      if (k0 + 63 > qbase) {
        const int qrow = qbase + lg * 4;
#pragma unroll
        for (int j = 0; j < 4; ++j) {
          const int kcol = k0 + j * 16 + l15;
#pragma unroll
          for (int r = 0; r < 4; ++r)
            if (kcol > qrow + r) s[j][r] = -1e30f;
        }
      }
#pragma unroll
      for (int j = 0; j < 4; ++j)
        s[j] = s[j] * SC2;

#pragma unroll
      for (int r = 0; r < 4; ++r) {
        float tm = fmaxf(fmaxf(s[0][r], s[1][r]), fmaxf(s[2][r], s[3][r]));
        tm = fmaxf(tm, __shfl_xor(tm, 1));
        tm = fmaxf(tm, __shfl_xor(tm, 2));
        tm = fmaxf(tm, __shfl_xor(tm, 4));
        tm = fmaxf(tm, __shfl_xor(tm, 8));
        float mn = fmaxf(mm[r], tm);
        float fac = __builtin_amdgcn_exp2f(mm[r] - mn);
        mm[r] = mn;
        float rs = 0.f;
#pragma unroll
        for (int j = 0; j < 4; ++j) {
          float pv = __builtin_amdgcn_exp2f(s[j][r] - mn);
          rs += pv;
          pbuf[wave][(lg * 4 + r) * 72 + j * 16 + l15] = (f16)pv;
        }
        rs += __shfl_xor(rs, 1);
        rs += __shfl_xor(rs, 2);
        rs += __shfl_xor(rs, 4);
        rs += __shfl_xor(rs, 8);
        ll[r] = ll[r] * fac + rs;
#pragma unroll
        for (int n = 0; n < 8; ++n) o[n][r] *= fac;
      }
      __syncthreads();

#pragma unroll
      for (int kc = 0; kc < 2; ++kc) {
        f16x8 pa = *(const f16x8*)(&pbuf[wave][l15 * 72 + kc * 32 + lg * 8]);
#pragma unroll
        for (int n = 0; n < 8; ++n) {
          const int vrow = n * 16 + l15;
          f16x8 vv = *(const f16x8*)(sV + vrow * 64 + (((kc * 32 + lg * 8)) ^ ((vrow & 7) << 3)));
          o[n] = mfma16(pa, vv, o[n]);
        }
      }
      __syncthreads();
    }

#pragma unroll
    for (int r = 0; r < 4; ++r) {
      float inv = 1.0f / ll[r];
      long rbase = (long)(b * 1024 + qbase + lg * 4 + r) * 2048 + h * 128;
#pragma unroll
      for (int n = 0; n < 8; ++n)
        Ctx[rbase + n * 16 + l15] = (f16)(o[n][r] * inv);
    }
  }
}

// ---------------- launch ----------------
extern "C" void kernel_launch(void* const* d_in, const int* in_sizes, int n_in,
                              void* d_out, int out_size, void* d_ws, size_t ws_size,
                              hipStream_t stream) {
  (void)in_sizes; (void)n_in; (void)out_size; (void)ws_size;
  const float* x  = (const float*)d_in[0];
  const float* Wq = (const float*)d_in[1];
  const float* Wk = (const float*)d_in[2];
  const float* Wv = (const float*)d_in[3];
  const float* Wo = (const float*)d_in[4];
  float* out = (float*)d_out;
  f16* ws = (f16*)d_ws;

  const long MD = 4096L * 2048;   // x / q / k / v / ctx elements
  const long DD = 2048L * 2048;   // weight elements

  f16* xh  = ws;                  // [MD]
  f16* xl  = ws + MD;             // [MD]
  f16* wqh = ws + 2 * MD;         // [DD] x6 weights
  f16* wql = wqh + DD;
  f16* wkh = wql + DD;
  f16* wkl = wkh + DD;
  f16* wv  = wkl + DD;
  f16* wo  = wv + DD;
  f16* qh  = wo + DD;             // [MD] x4
  f16* ql  = qh + MD;
  f16* kh  = ql + MD;
  f16* kl  = kh + MD;
  f16* vt  = kl + MD;             // [MD] V^T
  f16* vh  = xl;                  // alias: V (plain), xl dead after K-proj
  f16* ctx = xh;                  // alias: ctx, xh dead after V-proj

  conv_split_k<<<8192, 256, 0, stream>>>(x,  xh,  xl,  (int)(MD / 4));
  conv_split_k<<<4096, 256, 0, stream>>>(Wq, wqh, wql, (int)(DD / 4));
  conv_split_k<<<4096, 256, 0, stream>>>(Wk, wkh, wkl, (int)(DD / 4));
  conv_plain_k<<<4096, 256, 0, stream>>>(Wv, wv, (int)(DD / 4));
  conv_plain_k<<<4096, 256, 0, stream>>>(Wo, wo, (int)(DD / 4));

  dim3 gg(16, 32);  // (N/128, M/128)
  gemm_split<<<gg, 512, 0, stream>>>(xh, xl, wqh, wql, qh, ql, 2048, 2048);
  gemm_split<<<gg, 512, 0, stream>>>(xh, xl, wkh, wkl, kh, kl, 2048, 2048);
  gemm_bt<0><<<gg, 256, 0, stream>>>(xh, wv, vh, 2048, 2048);
  transpose_v_k<<<dim3(16, 2, 64), 256, 0, stream>>>(vh, vt);
  attn_k<<<dim3(64, 8), 256, 0, stream>>>(qh, ql, kh, kl, vt, ctx);
  gemm_bt<2><<<gg, 256, 0, stream>>>(ctx, wo, out, 2048, 2048);
}

// Round 5
// 394.244 us; speedup vs baseline: 1.3666x; 1.3666x over previous
//
#include <hip/hip_runtime.h>

// ---------------------------------------------------------------------------
// MHA block: x[4,1024,2048], W*[2048,2048] (torch Linear: y = x @ W^T)
//   q,k,v = x@W{q,k,v}^T ; scores = q k^T * sqrt(128) (causal) ; softmax ;
//   ctx = attn @ v ; out = ctx @ Wo^T
// R4: all-plain f16 (hi/lo split removed). Error budget: f16 Q/K logit err
// ~0.05 only matters on near-tie softmax rows; Wo projection attenuates
// attention-path errors ~0.23x -> predicted absmax 0.02-0.05 < 8.5e-2.
// ---------------------------------------------------------------------------

typedef _Float16 f16;
typedef _Float16 f16x8 __attribute__((ext_vector_type(8)));
typedef _Float16 f16x4 __attribute__((ext_vector_type(4)));
typedef float f32x4 __attribute__((ext_vector_type(4)));

__device__ __forceinline__ f32x4 mfma16(f16x8 a, f16x8 b, f32x4 c) {
  return __builtin_amdgcn_mfma_f32_16x16x32_f16(a, b, c, 0, 0, 0);
}

__device__ __forceinline__ void gld16(const void* g, void* l) {
  __builtin_amdgcn_global_load_lds(
      (const __attribute__((address_space(1))) void*)g,
      (__attribute__((address_space(3))) void*)l, 16, 0, 0);
}

// ---------------- conversion kernel ----------------
__global__ void conv_plain_k(const float* __restrict__ src, f16* __restrict__ dst, int n4) {
  int i = blockIdx.x * 256 + threadIdx.x;
  if (i >= n4) return;
  float4 v = reinterpret_cast<const float4*>(src)[i];
  f16x4 h;
  h[0] = (f16)v.x; h[1] = (f16)v.y; h[2] = (f16)v.z; h[3] = (f16)v.w;
  reinterpret_cast<f16x4*>(dst)[i] = h;
}

// ---------------- plain GEMM: C[M,N] = A[M,K] * B[N,K]^T ----------------
// 128x128 tile, BK=32, 256 threads (4 waves, 2x2 of 64x64), m97 2-barrier loop.
// OUTMODE: 0 = f16, 2 = f32
template<int OUTMODE>
__global__ __launch_bounds__(256, 2) void gemm_bt(
    const f16* __restrict__ Ah, const f16* __restrict__ Bh,
    void* __restrict__ C0, int Nn, int Kk)
{
  __shared__ f16 sAh[128 * 32];
  __shared__ f16 sBh[128 * 32];

  const int t = threadIdx.x;
  const int wave = t >> 6, lane = t & 63;
  const int l15 = lane & 15, lg = lane >> 4;
  const int wr = wave >> 1, wc = wave & 1;
  const long m0 = (long)blockIdx.y * 128, n0 = (long)blockIdx.x * 128;

  const int srow = t >> 2;            // 0..63
  const int scol = (t & 3) * 8;
  const long aoff = (m0 + srow) * (long)Kk + scol;
  const long boff = (n0 + srow) * (long)Kk + scol;
  const long rowstep = 64L * Kk;
  const int ldst = wave * 512;        // f16 elements, wave-uniform

  f32x4 acc[4][4] = {};
  const int lof = l15 * 32 + lg * 8;

  for (int k0 = 0; k0 < Kk; k0 += 32) {
    gld16(Ah + aoff + k0,           sAh + ldst);
    gld16(Ah + aoff + rowstep + k0, sAh + 2048 + ldst);
    gld16(Bh + boff + k0,           sBh + ldst);
    gld16(Bh + boff + rowstep + k0, sBh + 2048 + ldst);
    __syncthreads();
    f16x8 a_h[4], b_h[4];
#pragma unroll
    for (int i = 0; i < 4; ++i) a_h[i] = *(const f16x8*)(sAh + (wr * 64 + i * 16) * 32 + lof);
#pragma unroll
    for (int j = 0; j < 4; ++j) b_h[j] = *(const f16x8*)(sBh + (wc * 64 + j * 16) * 32 + lof);
#pragma unroll
    for (int i = 0; i < 4; ++i)
#pragma unroll
      for (int j = 0; j < 4; ++j)
        acc[i][j] = mfma16(a_h[i], b_h[j], acc[i][j]);
    __syncthreads();
  }

#pragma unroll
  for (int i = 0; i < 4; ++i)
#pragma unroll
    for (int j = 0; j < 4; ++j)
#pragma unroll
      for (int r = 0; r < 4; ++r) {
        long row = m0 + wr * 64 + i * 16 + lg * 4 + r;
        long col = n0 + wc * 64 + j * 16 + l15;
        long idx = row * Nn + col;
        float v = acc[i][j][r];
        if constexpr (OUTMODE == 0) {
          ((f16*)C0)[idx] = (f16)v;
        } else {
          ((float*)C0)[idx] = v;
        }
      }
}

// ---------------- V transpose: V[b*1024+s][h*128+d] -> Vt[(b*16+h)*128+d][s] ---
__global__ void transpose_v_k(const f16* __restrict__ V, f16* __restrict__ Vt) {
  const int st = blockIdx.x;      // 16 s-tiles of 64
  const int dt = blockIdx.y;      // 2 d-tiles of 64
  const int bh = blockIdx.z;      // 64
  const int b = bh >> 4, h = bh & 15;
  __shared__ f16 tile[64][68];
  const int t = threadIdx.x;
  const int r = t >> 4;
  const int c4 = (t & 15) * 4;
#pragma unroll
  for (int p = 0; p < 4; ++p) {
    int row = r + p * 16;
    f16x4 v = *(const f16x4*)(V + (long)(b * 1024 + st * 64 + row) * 2048 + h * 128 + dt * 64 + c4);
    tile[row][c4] = v[0]; tile[row][c4 + 1] = v[1];
    tile[row][c4 + 2] = v[2]; tile[row][c4 + 3] = v[3];
  }
  __syncthreads();
#pragma unroll
  for (int p = 0; p < 4; ++p) {
    int drow = r + p * 16;
    f16x4 o;
    o[0] = tile[c4][drow]; o[1] = tile[c4 + 1][drow];
    o[2] = tile[c4 + 2][drow]; o[3] = tile[c4 + 3][drow];
    *(f16x4*)(Vt + ((long)bh * 128 + dt * 64 + drow) * 1024 + st * 64 + c4) = o;
  }
}

// ---------------- causal flash attention (plain f16) ----------------
// grid (64 = h*4+b groups, 8 = p), 256 thr / 4 waves; each wave owns 16 q-rows.
// Block p processes q-tiles (15-p) then (p): uniform 17 k-tiles per block.
// K and V staged in LDS via gld16, XOR-swizzled (conflict-free ds_read_b128).
__global__ __launch_bounds__(256, 4) void attn_k(
    const f16* __restrict__ Qh, const f16* __restrict__ Kh,
    const f16* __restrict__ Vt, f16* __restrict__ Ctx)
{
  const int g = blockIdx.x;           // h*4 + b
  const int p = blockIdx.y;           // 0..7
  const int b = g & 3, h = g >> 2;
  const int t = threadIdx.x, wave = t >> 6, lane = t & 63;
  const int l15 = lane & 15, lg = lane >> 4;

  __shared__ f16 sKh[64 * 128];       // [krow][d], swizzled
  __shared__ f16 sV [128 * 64];       // [d][s], swizzled
  __shared__ f16 pbuf[4][16 * 72];    // per-wave P^T staging

  const long kbase = (long)(b * 1024) * 2048 + h * 128;
  const long vtb = (long)((b * 16 + h) * 128) * 1024;
  // softmax(scores * sqrt(128)) in exp2 domain: SC2 = sqrt(128)*log2(e)
  const float SC2 = (float)(11.313708498984761 * 1.4426950408889634);

  const int krow_s = t >> 4;                       // + q*16
  const int vrow_s = t >> 3;                       // + q*32

#pragma unroll
  for (int half = 0; half < 2; ++half) {
    const int myqt = half ? p : 15 - p;
    const int qbase = myqt * 64 + wave * 16;

    f16x8 q_h[4];
#pragma unroll
    for (int c = 0; c < 4; ++c) {
      long o8 = (long)(b * 1024 + qbase + l15) * 2048 + h * 128 + c * 32 + lg * 8;
      q_h[c] = *(const f16x8*)(Qh + o8);
    }

    float mm[4], ll[4];
#pragma unroll
    for (int r = 0; r < 4; ++r) { mm[r] = -1e30f; ll[r] = 0.f; }
    f32x4 o[8] = {};

    const int nt = myqt + 1;
    for (int kt = 0; kt < nt; ++kt) {
      const int k0 = kt * 64;
#pragma unroll
      for (int q = 0; q < 4; ++q) {
        const int row = q * 16 + krow_s;
        const int colx = ((t & 15) * 8) ^ ((row & 7) << 3);
        gld16(Kh + kbase + (long)(k0 + row) * 2048 + colx, sKh + q * 2048 + t * 8);
      }
#pragma unroll
      for (int q = 0; q < 4; ++q) {
        const int row = q * 32 + vrow_s;
        const int colx = ((t & 7) * 8) ^ ((row & 7) << 3);
        gld16(Vt + vtb + (long)row * 1024 + k0 + colx, sV + q * 2048 + t * 8);
      }
      __syncthreads();

      f32x4 s[4] = {};
#pragma unroll
      for (int c = 0; c < 4; ++c)
#pragma unroll
        for (int j = 0; j < 4; ++j) {
          const int krow = j * 16 + l15;
          const int koff = krow * 128 + (((c * 32 + lg * 8)) ^ ((krow & 7) << 3));
          f16x8 kh = *(const f16x8*)(sKh + koff);
          s[j] = mfma16(q_h[c], kh, s[j]);
        }

      if (k0 + 63 > qbase) {   // tile touches/crosses diagonal -> mask
        const int qrow = qbase + lg * 4;
#pragma unroll
        for (int j = 0; j < 4; ++j) {
          const int kcol = k0 + j * 16 + l15;
#pragma unroll
          for (int r = 0; r < 4; ++r)
            if (kcol > qrow + r) s[j][r] = -1e30f;
        }
      }
#pragma unroll
      for (int j = 0; j < 4; ++j)
        s[j] = s[j] * SC2;

#pragma unroll
      for (int r = 0; r < 4; ++r) {
        float tm = fmaxf(fmaxf(s[0][r], s[1][r]), fmaxf(s[2][r], s[3][r]));
        tm = fmaxf(tm, __shfl_xor(tm, 1));
        tm = fmaxf(tm, __shfl_xor(tm, 2));
        tm = fmaxf(tm, __shfl_xor(tm, 4));
        tm = fmaxf(tm, __shfl_xor(tm, 8));
        float mn = fmaxf(mm[r], tm);
        float fac = __builtin_amdgcn_exp2f(mm[r] - mn);
        mm[r] = mn;
        float rs = 0.f;
#pragma unroll
        for (int j = 0; j < 4; ++j) {
          float pv = __builtin_amdgcn_exp2f(s[j][r] - mn);
          rs += pv;
          pbuf[wave][(lg * 4 + r) * 72 + j * 16 + l15] = (f16)pv;
        }
        rs += __shfl_xor(rs, 1);
        rs += __shfl_xor(rs, 2);
        rs += __shfl_xor(rs, 4);
        rs += __shfl_xor(rs, 8);
        ll[r] = ll[r] * fac + rs;
#pragma unroll
        for (int n = 0; n < 8; ++n) o[n][r] *= fac;
      }
      __syncthreads();

#pragma unroll
      for (int kc = 0; kc < 2; ++kc) {
        f16x8 pa = *(const f16x8*)(&pbuf[wave][l15 * 72 + kc * 32 + lg * 8]);
#pragma unroll
        for (int n = 0; n < 8; ++n) {
          const int vrow = n * 16 + l15;
          f16x8 vv = *(const f16x8*)(sV + vrow * 64 + (((kc * 32 + lg * 8)) ^ ((vrow & 7) << 3)));
          o[n] = mfma16(pa, vv, o[n]);
        }
      }
      __syncthreads();
    }

#pragma unroll
    for (int r = 0; r < 4; ++r) {
      float inv = 1.0f / ll[r];
      long rbase = (long)(b * 1024 + qbase + lg * 4 + r) * 2048 + h * 128;
#pragma unroll
      for (int n = 0; n < 8; ++n)
        Ctx[rbase + n * 16 + l15] = (f16)(o[n][r] * inv);
    }
  }
}

// ---------------- launch ----------------
extern "C" void kernel_launch(void* const* d_in, const int* in_sizes, int n_in,
                              void* d_out, int out_size, void* d_ws, size_t ws_size,
                              hipStream_t stream) {
  (void)in_sizes; (void)n_in; (void)out_size; (void)ws_size;
  const float* x  = (const float*)d_in[0];
  const float* Wq = (const float*)d_in[1];
  const float* Wk = (const float*)d_in[2];
  const float* Wv = (const float*)d_in[3];
  const float* Wo = (const float*)d_in[4];
  float* out = (float*)d_out;
  f16* ws = (f16*)d_ws;

  const long MD = 4096L * 2048;   // x / q / k / v / ctx elements
  const long DD = 2048L * 2048;   // weight elements

  f16* xh = ws;                   // [MD]
  f16* wq = ws + MD;              // [DD] x4
  f16* wk = wq + DD;
  f16* wv = wk + DD;
  f16* wo = wv + DD;
  f16* qh = wo + DD;              // [MD] x4
  f16* kh = qh + MD;
  f16* vh = kh + MD;
  f16* vt = vh + MD;
  f16* ctx = xh;                  // alias: x dead after V-proj

  conv_plain_k<<<8192, 256, 0, stream>>>(x,  xh, (int)(MD / 4));
  conv_plain_k<<<4096, 256, 0, stream>>>(Wq, wq, (int)(DD / 4));
  conv_plain_k<<<4096, 256, 0, stream>>>(Wk, wk, (int)(DD / 4));
  conv_plain_k<<<4096, 256, 0, stream>>>(Wv, wv, (int)(DD / 4));
  conv_plain_k<<<4096, 256, 0, stream>>>(Wo, wo, (int)(DD / 4));

  dim3 gg(16, 32);  // (N/128, M/128)
  gemm_bt<0><<<gg, 256, 0, stream>>>(xh, wq, qh, 2048, 2048);
  gemm_bt<0><<<gg, 256, 0, stream>>>(xh, wk, kh, 2048, 2048);
  gemm_bt<0><<<gg, 256, 0, stream>>>(xh, wv, vh, 2048, 2048);
  transpose_v_k<<<dim3(16, 2, 64), 256, 0, stream>>>(vh, vt);
  attn_k<<<dim3(64, 8), 256, 0, stream>>>(qh, kh, vt, ctx);
  gemm_bt<2><<<gg, 256, 0, stream>>>(ctx, wo, out, 2048, 2048);
}

// Round 6
// 387.772 us; speedup vs baseline: 1.3894x; 1.0167x over previous
//
#include <hip/hip_runtime.h>

// ---------------------------------------------------------------------------
// MHA block: x[4,1024,2048], W*[2048,2048] (torch Linear: y = x @ W^T)
// R5: (1) QKV projections fused into ONE 256^2-tile 8-wave deep-pipelined GEMM
//     (BK=64, 4 phases/K-tile, counted-boundary vmcnt, T2 swizzle, setprio);
//     (2) attn gets T13 defer-max (skip O-rescale when max didn't grow >8).
// ---------------------------------------------------------------------------

typedef _Float16 f16;
typedef _Float16 f16x8 __attribute__((ext_vector_type(8)));
typedef _Float16 f16x4 __attribute__((ext_vector_type(4)));
typedef float f32x4 __attribute__((ext_vector_type(4)));

__device__ __forceinline__ f32x4 mfma16(f16x8 a, f16x8 b, f32x4 c) {
  return __builtin_amdgcn_mfma_f32_16x16x32_f16(a, b, c, 0, 0, 0);
}

__device__ __forceinline__ void gld16(const void* g, void* l) {
  __builtin_amdgcn_global_load_lds(
      (const __attribute__((address_space(1))) void*)g,
      (__attribute__((address_space(3))) void*)l, 16, 0, 0);
}

#define BAR() __builtin_amdgcn_s_barrier()
#define VMCNT0() asm volatile("s_waitcnt vmcnt(0)" ::: "memory")
#define LGKM0()                                        \
  do {                                                 \
    asm volatile("s_waitcnt lgkmcnt(0)" ::: "memory"); \
    __builtin_amdgcn_sched_barrier(0);                 \
  } while (0)

// ---------------- conversion kernel ----------------
__global__ void conv_plain_k(const float* __restrict__ src, f16* __restrict__ dst, int n4) {
  int i = blockIdx.x * 256 + threadIdx.x;
  if (i >= n4) return;
  float4 v = reinterpret_cast<const float4*>(src)[i];
  f16x4 h;
  h[0] = (f16)v.x; h[1] = (f16)v.y; h[2] = (f16)v.z; h[3] = (f16)v.w;
  reinterpret_cast<f16x4*>(dst)[i] = h;
}

// ---------------- fused QKV GEMM: C[4096,6144] = A[4096,2048] * W[6144,2048]^T
// 256x256 tile, BK=64, 512 thr / 8 waves (2Mx4N, wave tile 128x64).
// LDS: 2 dbuf x (sA[256][64] + sB[256][64]) f16 = 128 KB, XOR swizzle
// byte ^= ((row&7)<<4) (R2/R3-verified conflict-free).
// Schedule per K-tile: 4 phases = (m-half, k-half) quadrants, 16 MFMA each;
// b-frags of each k-half reused across both m-half phases. All 8 gld16 for
// tile kt+1 issued at P1 (into buf c^1, readers finished last iter); boundary
// vmcnt(0) at P4 waits on loads issued ~3 phases earlier. Raw s_barrier
// (no syncthreads drain); lgkmcnt(0)+sched_barrier before each MFMA cluster.
// Output col c in [0,6144) routed to Out + (c>>11)*MD (Q|K|V buffers).
__global__ __launch_bounds__(512, 1) void qkv_gemm(
    const f16* __restrict__ A, const f16* __restrict__ Wcat,
    f16* __restrict__ Out, int Kk)
{
  __shared__ f16 sA[2][256 * 64];
  __shared__ f16 sB[2][256 * 64];

  const int t = threadIdx.x;
  const int wave = t >> 6, lane = t & 63;
  const int l15 = lane & 15, lg = lane >> 4;
  const int wr = wave >> 2, wc = wave & 3;
  const long m0 = (long)blockIdx.y * 256;
  const long n0 = (long)blockIdx.x * 256;

  // staging: slot q covers rows q*64 + (t>>3); 16B per thread per slot.
  // logical col = phys ^ ((row&7)<<4)  (row&7 == (t>>3)&7, q*64 = 0 mod 8)
  const int crow = t >> 3;                                        // 0..63
  const int cf = ((((t & 7) * 16) ^ ((crow & 7) << 4)) >> 1);     // f16 col 0..63
  const f16* gA = A    + (m0 + crow) * (long)Kk + cf;
  const f16* gB = Wcat + (n0 + crow) * (long)Kk + cf;
  const long rq = 64L * Kk;
  const int dsb = t * 8;          // f16 offset, + q*4096

  // fragment read columns (f16 index within 64-col row)
  const int xorb = (l15 & 7) << 4;
  const int ac0 = ((lg * 16) ^ xorb) >> 1;          // k-half 0
  const int ac1 = (((lg * 16) + 64) ^ xorb) >> 1;   // k-half 1

  f32x4 acc[8][4] = {};

  const int NT = Kk >> 6;

  // prologue: stage tile 0 -> buf0
#pragma unroll
  for (int q = 0; q < 4; ++q) gld16(gA + q * rq, &sA[0][q * 4096 + dsb]);
#pragma unroll
  for (int q = 0; q < 4; ++q) gld16(gB + q * rq, &sB[0][q * 4096 + dsb]);
  VMCNT0();
  BAR();

  for (int kt = 0; kt < NT; ++kt) {
    const int c = kt & 1;
    const f16* pA = &sA[c][0];
    const f16* pB = &sB[c][0];
    const long gofs = (long)(kt + 1) * 64;

    // ---------- P1: b(kh0) + a(mh0,kh0); issue next tile ----------
    f16x8 b0[4], a0[4];
#pragma unroll
    for (int n = 0; n < 4; ++n) {
      const int row = wc * 64 + n * 16 + l15;
      b0[n] = *(const f16x8*)(pB + row * 64 + ac0);
    }
#pragma unroll
    for (int m = 0; m < 4; ++m) {
      const int row = wr * 128 + m * 16 + l15;
      a0[m] = *(const f16x8*)(pA + row * 64 + ac0);
    }
    if (kt + 1 < NT) {
#pragma unroll
      for (int q = 0; q < 4; ++q) gld16(gA + gofs + q * rq, &sA[c ^ 1][q * 4096 + dsb]);
#pragma unroll
      for (int q = 0; q < 4; ++q) gld16(gB + gofs + q * rq, &sB[c ^ 1][q * 4096 + dsb]);
    }
    BAR();
    LGKM0();
    __builtin_amdgcn_s_setprio(1);
#pragma unroll
    for (int m = 0; m < 4; ++m)
#pragma unroll
      for (int n = 0; n < 4; ++n)
        acc[m][n] = mfma16(a0[m], b0[n], acc[m][n]);
    __builtin_amdgcn_s_setprio(0);
    BAR();

    // ---------- P2: a(mh1,kh0) ----------
    f16x8 a1[4];
#pragma unroll
    for (int m = 0; m < 4; ++m) {
      const int row = wr * 128 + 64 + m * 16 + l15;
      a1[m] = *(const f16x8*)(pA + row * 64 + ac0);
    }
    BAR();
    LGKM0();
    __builtin_amdgcn_s_setprio(1);
#pragma unroll
    for (int m = 0; m < 4; ++m)
#pragma unroll
      for (int n = 0; n < 4; ++n)
        acc[4 + m][n] = mfma16(a1[m], b0[n], acc[4 + m][n]);
    __builtin_amdgcn_s_setprio(0);
    BAR();

    // ---------- P3: b(kh1) + a(mh0,kh1) ----------
    f16x8 b1[4], a2[4];
#pragma unroll
    for (int n = 0; n < 4; ++n) {
      const int row = wc * 64 + n * 16 + l15;
      b1[n] = *(const f16x8*)(pB + row * 64 + ac1);
    }
#pragma unroll
    for (int m = 0; m < 4; ++m) {
      const int row = wr * 128 + m * 16 + l15;
      a2[m] = *(const f16x8*)(pA + row * 64 + ac1);
    }
    BAR();
    LGKM0();
    __builtin_amdgcn_s_setprio(1);
#pragma unroll
    for (int m = 0; m < 4; ++m)
#pragma unroll
      for (int n = 0; n < 4; ++n)
        acc[m][n] = mfma16(a2[m], b1[n], acc[m][n]);
    __builtin_amdgcn_s_setprio(0);
    BAR();

    // ---------- P4: a(mh1,kh1); boundary counted wait ----------
    f16x8 a3[4];
#pragma unroll
    for (int m = 0; m < 4; ++m) {
      const int row = wr * 128 + 64 + m * 16 + l15;
      a3[m] = *(const f16x8*)(pA + row * 64 + ac1);
    }
    BAR();
    LGKM0();
    __builtin_amdgcn_s_setprio(1);
#pragma unroll
    for (int m = 0; m < 4; ++m)
#pragma unroll
      for (int n = 0; n < 4; ++n)
        acc[4 + m][n] = mfma16(a3[m], b1[n], acc[4 + m][n]);
    __builtin_amdgcn_s_setprio(0);
    if (kt + 1 < NT) VMCNT0();   // waits loads issued at P1 (~3 phases ago)
    BAR();
  }

  // epilogue: route to Q/K/V buffer by global column
  f16* base = Out + (long)(n0 >> 11) * (4096L * 2048);
  const int lc0 = (int)(n0 & 2047) + wc * 64;
#pragma unroll
  for (int m = 0; m < 8; ++m)
#pragma unroll
    for (int n = 0; n < 4; ++n)
#pragma unroll
      for (int r = 0; r < 4; ++r) {
        const long grow = m0 + wr * 128 + m * 16 + lg * 4 + r;
        base[grow * 2048 + lc0 + n * 16 + l15] = (f16)acc[m][n][r];
      }
}

// ---------------- plain GEMM: C[M,N] = A[M,K] * B[N,K]^T (out proj) --------
template<int OUTMODE>
__global__ __launch_bounds__(256, 2) void gemm_bt(
    const f16* __restrict__ Ah, const f16* __restrict__ Bh,
    void* __restrict__ C0, int Nn, int Kk)
{
  __shared__ f16 sAh[128 * 32];
  __shared__ f16 sBh[128 * 32];

  const int t = threadIdx.x;
  const int wave = t >> 6, lane = t & 63;
  const int l15 = lane & 15, lg = lane >> 4;
  const int wr = wave >> 1, wc = wave & 1;
  const long m0 = (long)blockIdx.y * 128, n0 = (long)blockIdx.x * 128;

  const int srow = t >> 2;            // 0..63
  const int scol = (t & 3) * 8;
  const long aoff = (m0 + srow) * (long)Kk + scol;
  const long boff = (n0 + srow) * (long)Kk + scol;
  const long rowstep = 64L * Kk;
  const int ldst = wave * 512;        // f16 elements, wave-uniform

  f32x4 acc[4][4] = {};
  const int lof = l15 * 32 + lg * 8;

  for (int k0 = 0; k0 < Kk; k0 += 32) {
    gld16(Ah + aoff + k0,           sAh + ldst);
    gld16(Ah + aoff + rowstep + k0, sAh + 2048 + ldst);
    gld16(Bh + boff + k0,           sBh + ldst);
    gld16(Bh + boff + rowstep + k0, sBh + 2048 + ldst);
    __syncthreads();
    f16x8 a_h[4], b_h[4];
#pragma unroll
    for (int i = 0; i < 4; ++i) a_h[i] = *(const f16x8*)(sAh + (wr * 64 + i * 16) * 32 + lof);
#pragma unroll
    for (int j = 0; j < 4; ++j) b_h[j] = *(const f16x8*)(sBh + (wc * 64 + j * 16) * 32 + lof);
#pragma unroll
    for (int i = 0; i < 4; ++i)
#pragma unroll
      for (int j = 0; j < 4; ++j)
        acc[i][j] = mfma16(a_h[i], b_h[j], acc[i][j]);
    __syncthreads();
  }

#pragma unroll
  for (int i = 0; i < 4; ++i)
#pragma unroll
    for (int j = 0; j < 4; ++j)
#pragma unroll
      for (int r = 0; r < 4; ++r) {
        long row = m0 + wr * 64 + i * 16 + lg * 4 + r;
        long col = n0 + wc * 64 + j * 16 + l15;
        long idx = row * Nn + col;
        float v = acc[i][j][r];
        if constexpr (OUTMODE == 0) {
          ((f16*)C0)[idx] = (f16)v;
        } else {
          ((float*)C0)[idx] = v;
        }
      }
}

// ---------------- V transpose: V[b*1024+s][h*128+d] -> Vt[(b*16+h)*128+d][s] ---
__global__ void transpose_v_k(const f16* __restrict__ V, f16* __restrict__ Vt) {
  const int st = blockIdx.x;      // 16 s-tiles of 64
  const int dt = blockIdx.y;      // 2 d-tiles of 64
  const int bh = blockIdx.z;      // 64
  const int b = bh >> 4, h = bh & 15;
  __shared__ f16 tile[64][68];
  const int t = threadIdx.x;
  const int r = t >> 4;
  const int c4 = (t & 15) * 4;
#pragma unroll
  for (int p = 0; p < 4; ++p) {
    int row = r + p * 16;
    f16x4 v = *(const f16x4*)(V + (long)(b * 1024 + st * 64 + row) * 2048 + h * 128 + dt * 64 + c4);
    tile[row][c4] = v[0]; tile[row][c4 + 1] = v[1];
    tile[row][c4 + 2] = v[2]; tile[row][c4 + 3] = v[3];
  }
  __syncthreads();
#pragma unroll
  for (int p = 0; p < 4; ++p) {
    int drow = r + p * 16;
    f16x4 o;
    o[0] = tile[c4][drow]; o[1] = tile[c4 + 1][drow];
    o[2] = tile[c4 + 2][drow]; o[3] = tile[c4 + 3][drow];
    *(f16x4*)(Vt + ((long)bh * 128 + dt * 64 + drow) * 1024 + st * 64 + c4) = o;
  }
}

// ---------------- causal flash attention (plain f16, T13 defer-max) --------
__global__ __launch_bounds__(256, 4) void attn_k(
    const f16* __restrict__ Qh, const f16* __restrict__ Kh,
    const f16* __restrict__ Vt, f16* __restrict__ Ctx)
{
  const int g = blockIdx.x;           // h*4 + b
  const int p = blockIdx.y;           // 0..7
  const int b = g & 3, h = g >> 2;
  const int t = threadIdx.x, wave = t >> 6, lane = t & 63;
  const int l15 = lane & 15, lg = lane >> 4;

  __shared__ f16 sKh[64 * 128];       // [krow][d], swizzled
  __shared__ f16 sV [128 * 64];       // [d][s], swizzled
  __shared__ f16 pbuf[4][16 * 72];    // per-wave P^T staging

  const long kbase = (long)(b * 1024) * 2048 + h * 128;
  const long vtb = (long)((b * 16 + h) * 128) * 1024;
  const float SC2 = (float)(11.313708498984761 * 1.4426950408889634);

  const int krow_s = t >> 4;                       // + q*16
  const int vrow_s = t >> 3;                       // + q*32

#pragma unroll
  for (int half = 0; half < 2; ++half) {
    const int myqt = half ? p : 15 - p;
    const int qbase = myqt * 64 + wave * 16;

    f16x8 q_h[4];
#pragma unroll
    for (int c = 0; c < 4; ++c) {
      long o8 = (long)(b * 1024 + qbase + l15) * 2048 + h * 128 + c * 32 + lg * 8;
      q_h[c] = *(const f16x8*)(Qh + o8);
    }

    float mm[4], ll[4];
#pragma unroll
    for (int r = 0; r < 4; ++r) { mm[r] = -1e30f; ll[r] = 0.f; }
    f32x4 o[8] = {};

    const int nt = myqt + 1;
    for (int kt = 0; kt < nt; ++kt) {
      const int k0 = kt * 64;
#pragma unroll
      for (int q = 0; q < 4; ++q) {
        const int row = q * 16 + krow_s;
        const int colx = ((t & 15) * 8) ^ ((row & 7) << 3);
        gld16(Kh + kbase + (long)(k0 + row) * 2048 + colx, sKh + q * 2048 + t * 8);
      }
#pragma unroll
      for (int q = 0; q < 4; ++q) {
        const int row = q * 32 + vrow_s;
        const int colx = ((t & 7) * 8) ^ ((row & 7) << 3);
        gld16(Vt + vtb + (long)row * 1024 + k0 + colx, sV + q * 2048 + t * 8);
      }
      __syncthreads();

      f32x4 s[4] = {};
#pragma unroll
      for (int c = 0; c < 4; ++c)
#pragma unroll
        for (int j = 0; j < 4; ++j) {
          const int krow = j * 16 + l15;
          const int koff = krow * 128 + (((c * 32 + lg * 8)) ^ ((krow & 7) << 3));
          f16x8 kh = *(const f16x8*)(sKh + koff);
          s[j] = mfma16(q_h[c], kh, s[j]);
        }

      if (k0 + 63 > qbase) {   // tile touches/crosses diagonal -> mask
        const int qrow = qbase + lg * 4;
#pragma unroll
        for (int j = 0; j < 4; ++j) {
          const int kcol = k0 + j * 16 + l15;
#pragma unroll
          for (int r = 0; r < 4; ++r)
            if (kcol > qrow + r) s[j][r] = -1e30f;
        }
      }
#pragma unroll
      for (int j = 0; j < 4; ++j)
        s[j] = s[j] * SC2;

#pragma unroll
      for (int r = 0; r < 4; ++r) {
        float tm = fmaxf(fmaxf(s[0][r], s[1][r]), fmaxf(s[2][r], s[3][r]));
        tm = fmaxf(tm, __shfl_xor(tm, 1));
        tm = fmaxf(tm, __shfl_xor(tm, 2));
        tm = fmaxf(tm, __shfl_xor(tm, 4));
        tm = fmaxf(tm, __shfl_xor(tm, 8));
        // T13 defer-max: only rescale when the tile max grew past m+8
        if (!__all(tm - mm[r] <= 8.0f)) {
          float mn = fmaxf(mm[r], tm);
          float fac = __builtin_amdgcn_exp2f(mm[r] - mn);
          mm[r] = mn;
          ll[r] *= fac;
#pragma unroll
          for (int n = 0; n < 8; ++n) o[n][r] *= fac;
        }
        float rs = 0.f;
#pragma unroll
        for (int j = 0; j < 4; ++j) {
          float pv = __builtin_amdgcn_exp2f(s[j][r] - mm[r]);
          rs += pv;
          pbuf[wave][(lg * 4 + r) * 72 + j * 16 + l15] = (f16)pv;
        }
        rs += __shfl_xor(rs, 1);
        rs += __shfl_xor(rs, 2);
        rs += __shfl_xor(rs, 4);
        rs += __shfl_xor(rs, 8);
        ll[r] += rs;
      }
      __syncthreads();

#pragma unroll
      for (int kc = 0; kc < 2; ++kc) {
        f16x8 pa = *(const f16x8*)(&pbuf[wave][l15 * 72 + kc * 32 + lg * 8]);
#pragma unroll
        for (int n = 0; n < 8; ++n) {
          const int vrow = n * 16 + l15;
          f16x8 vv = *(const f16x8*)(sV + vrow * 64 + (((kc * 32 + lg * 8)) ^ ((vrow & 7) << 3)));
          o[n] = mfma16(pa, vv, o[n]);
        }
      }
      __syncthreads();
    }

#pragma unroll
    for (int r = 0; r < 4; ++r) {
      float inv = 1.0f / ll[r];
      long rbase = (long)(b * 1024 + qbase + lg * 4 + r) * 2048 + h * 128;
#pragma unroll
      for (int n = 0; n < 8; ++n)
        Ctx[rbase + n * 16 + l15] = (f16)(o[n][r] * inv);
    }
  }
}

// ---------------- launch ----------------
extern "C" void kernel_launch(void* const* d_in, const int* in_sizes, int n_in,
                              void* d_out, int out_size, void* d_ws, size_t ws_size,
                              hipStream_t stream) {
  (void)in_sizes; (void)n_in; (void)out_size; (void)ws_size;
  const float* x  = (const float*)d_in[0];
  const float* Wq = (const float*)d_in[1];
  const float* Wk = (const float*)d_in[2];
  const float* Wv = (const float*)d_in[3];
  const float* Wo = (const float*)d_in[4];
  float* out = (float*)d_out;
  f16* ws = (f16*)d_ws;

  const long MD = 4096L * 2048;   // x / q / k / v / ctx elements
  const long DD = 2048L * 2048;   // weight elements

  f16* xh = ws;                   // [MD]
  f16* wq = ws + MD;              // [DD] x4 (wq,wk,wv contiguous = Wcat[6144][2048])
  f16* wk = wq + DD;
  f16* wv = wk + DD;
  f16* wo = wv + DD;
  f16* qh = wo + DD;              // [MD] x4 (qh,kh,vh contiguous for qkv routing)
  f16* kh = qh + MD;
  f16* vh = kh + MD;
  f16* vt = vh + MD;
  f16* ctx = xh;                  // alias: x dead after QKV proj

  conv_plain_k<<<8192, 256, 0, stream>>>(x,  xh, (int)(MD / 4));
  conv_plain_k<<<4096, 256, 0, stream>>>(Wq, wq, (int)(DD / 4));
  conv_plain_k<<<4096, 256, 0, stream>>>(Wk, wk, (int)(DD / 4));
  conv_plain_k<<<4096, 256, 0, stream>>>(Wv, wv, (int)(DD / 4));
  conv_plain_k<<<4096, 256, 0, stream>>>(Wo, wo, (int)(DD / 4));

  qkv_gemm<<<dim3(24, 16), 512, 0, stream>>>(xh, wq, qh, 2048);
  transpose_v_k<<<dim3(16, 2, 64), 256, 0, stream>>>(vh, vt);
  attn_k<<<dim3(64, 8), 256, 0, stream>>>(qh, kh, vt, ctx);
  gemm_bt<2><<<dim3(16, 32), 256, 0, stream>>>(ctx, wo, out, 2048, 2048);
}